// Round 3
// baseline (787.245 us; speedup 1.0000x reference)
//
#include <hip/hip_runtime.h>

#define HXc 64
#define HYc 64
#define Uc  512
#define Vc  512
#define Lc  16
#define NBUCK 8192   // 8 m  x  32 v-slabs  x  32 u-slabs

typedef float v4f __attribute__((ext_vector_type(4)));

// ---------------- shared index helpers ----------------

__device__ __forceinline__ void compute_inds(float h0, float h1, float uu, float vv,
                                             float& ix, float& iy, float& iu, float& iv) {
    ix = (h0 + 1.0f) * 0.5f * (float)HXc; if (ix == (float)HXc) ix = (float)(HXc - 1);
    iy = (h1 + 1.0f) * 0.5f * (float)HYc; if (iy == (float)HYc) iy = (float)(HYc - 1);
    iu = uu * (float)Uc;                  if (iu == (float)Uc)  iu = (float)(Uc - 1);
    iv = vv * (float)Vc;                  if (iv == (float)Vc)  iv = (float)(Vc - 1);
}

__device__ __forceinline__ int bucket_of(int mm, float iu, float iv) {
    int us = ((int)iu) >> 4;   // 0..31
    int vs = ((int)iv) >> 4;   // 0..31
    return (((mm << 5) | vs) << 5) | us;
}

// ---------------- pass 0: zero histogram ----------------

__global__ __launch_bounds__(256) void zero_kernel(int* __restrict__ counts) {
    int i = blockIdx.x * 256 + threadIdx.x;
    if (i < NBUCK) counts[i] = 0;
}

// ---------------- pass 1: histogram ----------------

__global__ __launch_bounds__(256) void hist_kernel(
    const int* __restrict__ m_arr, const float* __restrict__ u_arr,
    const float* __restrict__ v_arr, int* __restrict__ counts, int N)
{
    int n = blockIdx.x * 256 + threadIdx.x;
    if (n >= N) return;
    float iu = u_arr[n] * (float)Uc; if (iu == (float)Uc) iu = (float)(Uc - 1);
    float iv = v_arr[n] * (float)Vc; if (iv == (float)Vc) iv = (float)(Vc - 1);
    atomicAdd(&counts[bucket_of(m_arr[n], iu, iv)], 1);
}

// ---------------- pass 2: exclusive scan (single block) ----------------

__global__ __launch_bounds__(1024) void scan_kernel(
    const int* __restrict__ counts, int* __restrict__ cursors)
{
    __shared__ int lds[1024];
    int t = threadIdx.x;               // 0..1023, each owns 8 buckets
    int base = t * 8;
    int s = 0;
    #pragma unroll
    for (int k = 0; k < 8; ++k) s += counts[base + k];
    lds[t] = s;
    __syncthreads();
    // Hillis-Steele inclusive scan over 1024 partials
    for (int off = 1; off < 1024; off <<= 1) {
        int val = (t >= off) ? lds[t - off] : 0;
        __syncthreads();
        lds[t] += val;
        __syncthreads();
    }
    int run = lds[t] - s;              // exclusive base for this thread's 8 buckets
    #pragma unroll
    for (int k = 0; k < 8; ++k) {
        cursors[base + k] = run;
        run += counts[base + k];
    }
}

// ---------------- pass 3: scatter packed records ----------------

__global__ __launch_bounds__(256) void scatter_kernel(
    const int* __restrict__ m_arr, const float* __restrict__ h,
    const float* __restrict__ u_arr, const float* __restrict__ v_arr,
    int* __restrict__ cursors,
    v4f* __restrict__ inds4, int* __restrict__ m_s, int* __restrict__ outidx,
    int N)
{
    int n = blockIdx.x * 256 + threadIdx.x;
    if (n >= N) return;
    float h0 = h[2 * n], h1 = h[2 * n + 1];
    float ix, iy, iu, iv;
    compute_inds(h0, h1, u_arr[n], v_arr[n], ix, iy, iu, iv);
    int mm = m_arr[n];
    int b  = bucket_of(mm, iu, iv);
    int pos = atomicAdd(&cursors[b], 1);
    v4f rec; rec.x = ix; rec.y = iy; rec.z = iu; rec.w = iv;
    inds4[pos]  = rec;
    m_s[pos]    = mm;
    outidx[pos] = n;
}

// ---------------- pass 4: main gather ----------------

struct BL {
    const float* a11; const float* a21; const float* a12; const float* a22;
    float ir, jr;
};

__device__ __forceinline__ v4f ld4(const float* p) {
    return *reinterpret_cast<const v4f*>(p);
}

__device__ __forceinline__ BL mk(const float* __restrict__ base, int mm,
                                 float fi, float fj, int I, int J, int chan) {
    BL b;
    int i1 = (int)floorf(fi);
    int j1 = (int)floorf(fj);
    b.ir = fi - (float)i1;
    b.jr = fj - (float)j1;
    int i2 = (i1 + 1 == I) ? 0 : (i1 + 1);
    int j2 = (j1 + 1 == J) ? 0 : (j1 + 1);
    const float* p = base + ((size_t)mm * I * J) * Lc + chan;
    b.a11 = p + (size_t)(i1 * J + j1) * Lc;
    b.a21 = p + (size_t)(i2 * J + j1) * Lc;
    b.a12 = p + (size_t)(i1 * J + j2) * Lc;
    b.a22 = p + (size_t)(i2 * J + j2) * Lc;
    return b;
}

__device__ __forceinline__ v4f blend(v4f c11, v4f c21, v4f c12, v4f c22,
                                     float ir, float jr) {
    float oir = 1.0f - ir;
    float ojr = 1.0f - jr;
    v4f top = c11 * oir + c21 * ir;
    v4f bot = c12 * oir + c22 * ir;
    return top * ojr + bot * jr;
}

__global__ __launch_bounds__(256) void main_kernel(
    const v4f* __restrict__ inds4, const int* __restrict__ m_s,
    const int* __restrict__ outidx,
    const float* __restrict__ Fxy, const float* __restrict__ Fxu,
    const float* __restrict__ Fxv, const float* __restrict__ Fyu,
    const float* __restrict__ Fyv, const float* __restrict__ Fuv,
    float* __restrict__ out, int N, int nwg)
{
    // bijective XCD-chunked swizzle: each XCD gets a contiguous chunk of the
    // sorted stream -> its private L2 stays on one (m, v) region.
    int bid = blockIdx.x;
    int q = nwg >> 3, r = nwg & 7;
    int xcd = bid & 7, idx = bid >> 3;
    int swz = (xcd < r) ? (xcd * (q + 1) + idx) : (r * (q + 1) + (xcd - r) * q + idx);

    int t   = swz * 256 + threadIdx.x;
    int k   = t >> 2;     // sorted-point index
    int sub = t & 3;      // which float4 slice of the 16 channels
    if (k >= N) return;

    v4f inds = inds4[k];
    int mm   = m_s[k];
    int n    = outidx[k];
    float ind_hx = inds.x, ind_hy = inds.y, ind_u = inds.z, ind_v = inds.w;

    int chan = sub * 4;

    BL b0 = mk(Fxy, mm, ind_hx, ind_hy, HXc, HYc, chan);
    BL b1 = mk(Fxu, mm, ind_hx, ind_u,  HXc, Uc,  chan);
    BL b2 = mk(Fxv, mm, ind_hx, ind_v,  HXc, Vc,  chan);
    BL b3 = mk(Fyu, mm, ind_hy, ind_u,  HYc, Uc,  chan);
    BL b4 = mk(Fyv, mm, ind_hy, ind_v,  HYc, Vc,  chan);
    BL b5 = mk(Fuv, mm, ind_u,  ind_v,  Uc,  Vc,  chan);

    // batch all 24 loads before consumption (kept from R2 — neutral cost,
    // helps when bucket-local lines are L2-resident)
    v4f c0a = ld4(b0.a11); v4f c0b = ld4(b0.a21); v4f c0c = ld4(b0.a12); v4f c0d = ld4(b0.a22);
    v4f c1a = ld4(b1.a11); v4f c1b = ld4(b1.a21); v4f c1c = ld4(b1.a12); v4f c1d = ld4(b1.a22);
    v4f c2a = ld4(b2.a11); v4f c2b = ld4(b2.a21); v4f c2c = ld4(b2.a12); v4f c2d = ld4(b2.a22);
    v4f c3a = ld4(b3.a11); v4f c3b = ld4(b3.a21); v4f c3c = ld4(b3.a12); v4f c3d = ld4(b3.a22);
    v4f c4a = ld4(b4.a11); v4f c4b = ld4(b4.a21); v4f c4c = ld4(b4.a12); v4f c4d = ld4(b4.a22);
    v4f c5a = ld4(b5.a11); v4f c5b = ld4(b5.a21); v4f c5c = ld4(b5.a12); v4f c5d = ld4(b5.a22);

    __builtin_amdgcn_sched_barrier(0);

    float* o = out + (size_t)n * 96 + chan;

    *reinterpret_cast<v4f*>(o + 0 * Lc) = blend(c0a, c0b, c0c, c0d, b0.ir, b0.jr);
    *reinterpret_cast<v4f*>(o + 1 * Lc) = blend(c1a, c1b, c1c, c1d, b1.ir, b1.jr);
    *reinterpret_cast<v4f*>(o + 2 * Lc) = blend(c2a, c2b, c2c, c2d, b2.ir, b2.jr);
    *reinterpret_cast<v4f*>(o + 3 * Lc) = blend(c3a, c3b, c3c, c3d, b3.ir, b3.jr);
    *reinterpret_cast<v4f*>(o + 4 * Lc) = blend(c4a, c4b, c4c, c4d, b4.ir, b4.jr);
    *reinterpret_cast<v4f*>(o + 5 * Lc) = blend(c5a, c5b, c5c, c5d, b5.ir, b5.jr);
}

// ---------------- fallback (flat) kernel: R2 structure, normal stores ----------------

__global__ __launch_bounds__(256) void flat_kernel(
    const int*   __restrict__ m_arr,
    const float* __restrict__ h,
    const float* __restrict__ u_arr,
    const float* __restrict__ v_arr,
    const float* __restrict__ Fxy, const float* __restrict__ Fxu,
    const float* __restrict__ Fxv, const float* __restrict__ Fyu,
    const float* __restrict__ Fyv, const float* __restrict__ Fuv,
    float* __restrict__ out, int N)
{
    int tid = blockIdx.x * blockDim.x + threadIdx.x;
    int n   = tid >> 2;
    int sub = tid & 3;
    if (n >= N) return;

    float h0 = h[2 * n], h1 = h[2 * n + 1];
    float ind_hx, ind_hy, ind_u, ind_v;
    compute_inds(h0, h1, u_arr[n], v_arr[n], ind_hx, ind_hy, ind_u, ind_v);
    int mm = m_arr[n];
    int chan = sub * 4;

    BL b0 = mk(Fxy, mm, ind_hx, ind_hy, HXc, HYc, chan);
    BL b1 = mk(Fxu, mm, ind_hx, ind_u,  HXc, Uc,  chan);
    BL b2 = mk(Fxv, mm, ind_hx, ind_v,  HXc, Vc,  chan);
    BL b3 = mk(Fyu, mm, ind_hy, ind_u,  HYc, Uc,  chan);
    BL b4 = mk(Fyv, mm, ind_hy, ind_v,  HYc, Vc,  chan);
    BL b5 = mk(Fuv, mm, ind_u,  ind_v,  Uc,  Vc,  chan);

    v4f c0a = ld4(b0.a11); v4f c0b = ld4(b0.a21); v4f c0c = ld4(b0.a12); v4f c0d = ld4(b0.a22);
    v4f c1a = ld4(b1.a11); v4f c1b = ld4(b1.a21); v4f c1c = ld4(b1.a12); v4f c1d = ld4(b1.a22);
    v4f c2a = ld4(b2.a11); v4f c2b = ld4(b2.a21); v4f c2c = ld4(b2.a12); v4f c2d = ld4(b2.a22);
    v4f c3a = ld4(b3.a11); v4f c3b = ld4(b3.a21); v4f c3c = ld4(b3.a12); v4f c3d = ld4(b3.a22);
    v4f c4a = ld4(b4.a11); v4f c4b = ld4(b4.a21); v4f c4c = ld4(b4.a12); v4f c4d = ld4(b4.a22);
    v4f c5a = ld4(b5.a11); v4f c5b = ld4(b5.a21); v4f c5c = ld4(b5.a12); v4f c5d = ld4(b5.a22);

    __builtin_amdgcn_sched_barrier(0);

    float* o = out + (size_t)n * 96 + chan;
    *reinterpret_cast<v4f*>(o + 0 * Lc) = blend(c0a, c0b, c0c, c0d, b0.ir, b0.jr);
    *reinterpret_cast<v4f*>(o + 1 * Lc) = blend(c1a, c1b, c1c, c1d, b1.ir, b1.jr);
    *reinterpret_cast<v4f*>(o + 2 * Lc) = blend(c2a, c2b, c2c, c2d, b2.ir, b2.jr);
    *reinterpret_cast<v4f*>(o + 3 * Lc) = blend(c3a, c3b, c3c, c3d, b3.ir, b3.jr);
    *reinterpret_cast<v4f*>(o + 4 * Lc) = blend(c4a, c4b, c4c, c4d, b4.ir, b4.jr);
    *reinterpret_cast<v4f*>(o + 5 * Lc) = blend(c5a, c5b, c5c, c5d, b5.ir, b5.jr);
}

// ---------------- host launch ----------------

extern "C" void kernel_launch(void* const* d_in, const int* in_sizes, int n_in,
                              void* d_out, int out_size, void* d_ws, size_t ws_size,
                              hipStream_t stream) {
    // setup_inputs order: r(unused), m, h, u, v, Fxy, Fxu, Fxv, Fyu, Fyv, Fuv
    const int*   m_arr = (const int*)  d_in[1];
    const float* h     = (const float*)d_in[2];
    const float* u_arr = (const float*)d_in[3];
    const float* v_arr = (const float*)d_in[4];
    const float* Fxy   = (const float*)d_in[5];
    const float* Fxu   = (const float*)d_in[6];
    const float* Fxv   = (const float*)d_in[7];
    const float* Fyu   = (const float*)d_in[8];
    const float* Fyv   = (const float*)d_in[9];
    const float* Fuv   = (const float*)d_in[10];
    float* out = (float*)d_out;

    int N = in_sizes[0];

    // workspace layout
    size_t off_counts  = 0;
    size_t off_cursors = off_counts  + (size_t)NBUCK * 4;
    size_t off_inds4   = off_cursors + (size_t)NBUCK * 4;      // 16-B aligned (64 KiB)
    size_t off_ms      = off_inds4   + (size_t)N * 16;
    size_t off_outidx  = off_ms      + (size_t)N * 4;
    size_t needed      = off_outidx  + (size_t)N * 4;

    if (d_ws == nullptr || ws_size < needed) {
        // fallback: flat kernel (R2 structure, normal stores)
        int total_threads = 4 * N;
        dim3 block(256);
        dim3 grid((total_threads + 255) / 256);
        flat_kernel<<<grid, block, 0, stream>>>(m_arr, h, u_arr, v_arr,
                                                Fxy, Fxu, Fxv, Fyu, Fyv, Fuv, out, N);
        return;
    }

    char* ws = (char*)d_ws;
    int* counts  = (int*)(ws + off_counts);
    int* cursors = (int*)(ws + off_cursors);
    v4f* inds4   = (v4f*)(ws + off_inds4);
    int* m_s     = (int*)(ws + off_ms);
    int* outidx  = (int*)(ws + off_outidx);

    dim3 blk(256);
    dim3 grdN((N + 255) / 256);

    zero_kernel<<<dim3((NBUCK + 255) / 256), blk, 0, stream>>>(counts);
    hist_kernel<<<grdN, blk, 0, stream>>>(m_arr, u_arr, v_arr, counts, N);
    scan_kernel<<<dim3(1), dim3(1024), 0, stream>>>(counts, cursors);
    scatter_kernel<<<grdN, blk, 0, stream>>>(m_arr, h, u_arr, v_arr, cursors,
                                             inds4, m_s, outidx, N);

    int total_threads = 4 * N;
    int nwg = (total_threads + 255) / 256;
    main_kernel<<<dim3(nwg), blk, 0, stream>>>(inds4, m_s, outidx,
                                               Fxy, Fxu, Fxv, Fyu, Fyv, Fuv,
                                               out, N, nwg);
}

// Round 4
// 779.918 us; speedup vs baseline: 1.0094x; 1.0094x over previous
//
#include <hip/hip_runtime.h>

#define HXc 64
#define HYc 64
#define Uc  512
#define Vc  512
#define Lc  16
#define NBUCK 8192   // 8 m  x  32 v-slabs  x  32 u-slabs

typedef float    v4f __attribute__((ext_vector_type(4)));
typedef _Float16 h8  __attribute__((ext_vector_type(8)));

// ---------------- shared index helpers ----------------

__device__ __forceinline__ void compute_inds(float h0, float h1, float uu, float vv,
                                             float& ix, float& iy, float& iu, float& iv) {
    ix = (h0 + 1.0f) * 0.5f * (float)HXc; if (ix == (float)HXc) ix = (float)(HXc - 1);
    iy = (h1 + 1.0f) * 0.5f * (float)HYc; if (iy == (float)HYc) iy = (float)(HYc - 1);
    iu = uu * (float)Uc;                  if (iu == (float)Uc)  iu = (float)(Uc - 1);
    iv = vv * (float)Vc;                  if (iv == (float)Vc)  iv = (float)(Vc - 1);
}

__device__ __forceinline__ int bucket_of(int mm, float iu, float iv) {
    int us = ((int)iu) >> 4;   // 0..31
    int vs = ((int)iv) >> 4;   // 0..31
    return (((mm << 5) | vs) << 5) | us;
}

// ---------------- f32 -> f16 table conversion ----------------

__global__ __launch_bounds__(256) void convert_kernel(
    const float* __restrict__ src, _Float16* __restrict__ dst, int n8)
{
    int i = blockIdx.x * 256 + threadIdx.x;
    if (i >= n8) return;
    const v4f* s4 = reinterpret_cast<const v4f*>(src);
    v4f a = s4[2 * i];
    v4f b = s4[2 * i + 1];
    h8 o;
    o[0] = (_Float16)a.x; o[1] = (_Float16)a.y; o[2] = (_Float16)a.z; o[3] = (_Float16)a.w;
    o[4] = (_Float16)b.x; o[5] = (_Float16)b.y; o[6] = (_Float16)b.z; o[7] = (_Float16)b.w;
    *reinterpret_cast<h8*>(dst + 8 * (size_t)i) = o;
}

// ---------------- pass 0: zero histogram ----------------

__global__ __launch_bounds__(256) void zero_kernel(int* __restrict__ counts) {
    int i = blockIdx.x * 256 + threadIdx.x;
    if (i < NBUCK) counts[i] = 0;
}

// ---------------- pass 1: histogram (4 pts/thread) ----------------

__global__ __launch_bounds__(256) void hist_kernel(
    const int* __restrict__ m_arr, const float* __restrict__ u_arr,
    const float* __restrict__ v_arr, int* __restrict__ counts, int N)
{
    int base = (blockIdx.x * 256 + threadIdx.x) * 4;
    if (base >= N) return;
    if (base + 3 < N) {
        v4f u4 = *reinterpret_cast<const v4f*>(u_arr + base);
        v4f vv4 = *reinterpret_cast<const v4f*>(v_arr + base);
        int4 m4 = *reinterpret_cast<const int4*>(m_arr + base);
        #pragma unroll
        for (int k = 0; k < 4; ++k) {
            float iu = ((const float*)&u4)[k] * (float)Uc; if (iu == (float)Uc) iu = (float)(Uc - 1);
            float iv = ((const float*)&vv4)[k] * (float)Vc; if (iv == (float)Vc) iv = (float)(Vc - 1);
            atomicAdd(&counts[bucket_of(((const int*)&m4)[k], iu, iv)], 1);
        }
    } else {
        for (int n = base; n < N; ++n) {
            float iu = u_arr[n] * (float)Uc; if (iu == (float)Uc) iu = (float)(Uc - 1);
            float iv = v_arr[n] * (float)Vc; if (iv == (float)Vc) iv = (float)(Vc - 1);
            atomicAdd(&counts[bucket_of(m_arr[n], iu, iv)], 1);
        }
    }
}

// ---------------- pass 2: exclusive scan (single block) ----------------

__global__ __launch_bounds__(1024) void scan_kernel(
    const int* __restrict__ counts, int* __restrict__ cursors)
{
    __shared__ int lds[1024];
    int t = threadIdx.x;               // each owns 8 buckets
    int base = t * 8;
    int s = 0;
    #pragma unroll
    for (int k = 0; k < 8; ++k) s += counts[base + k];
    lds[t] = s;
    __syncthreads();
    for (int off = 1; off < 1024; off <<= 1) {
        int val = (t >= off) ? lds[t - off] : 0;
        __syncthreads();
        lds[t] += val;
        __syncthreads();
    }
    int run = lds[t] - s;
    #pragma unroll
    for (int k = 0; k < 8; ++k) {
        cursors[base + k] = run;
        run += counts[base + k];
    }
}

// ---------------- pass 3: scatter packed records ----------------

__global__ __launch_bounds__(256) void scatter_kernel(
    const int* __restrict__ m_arr, const float* __restrict__ h,
    const float* __restrict__ u_arr, const float* __restrict__ v_arr,
    int* __restrict__ cursors,
    v4f* __restrict__ inds4, unsigned int* __restrict__ keys,
    int N)
{
    int n = blockIdx.x * 256 + threadIdx.x;
    if (n >= N) return;
    float h0 = h[2 * n], h1 = h[2 * n + 1];
    float ix, iy, iu, iv;
    compute_inds(h0, h1, u_arr[n], v_arr[n], ix, iy, iu, iv);
    int mm = m_arr[n];
    int b  = bucket_of(mm, iu, iv);
    int pos = atomicAdd(&cursors[b], 1);
    v4f rec; rec.x = ix; rec.y = iy; rec.z = iu; rec.w = iv;
    inds4[pos] = rec;
    keys[pos]  = (unsigned int)n | ((unsigned int)mm << 24);
}

// ---------------- pass 4 (fp16): main gather, 2 threads per point ----------------

struct F8 { v4f lo, hi; };

__device__ __forceinline__ F8 cvt8(h8 x) {
    F8 r;
    r.lo.x = (float)x[0]; r.lo.y = (float)x[1]; r.lo.z = (float)x[2]; r.lo.w = (float)x[3];
    r.hi.x = (float)x[4]; r.hi.y = (float)x[5]; r.hi.z = (float)x[6]; r.hi.w = (float)x[7];
    return r;
}

struct BLH {
    const _Float16* a11; const _Float16* a21; const _Float16* a12; const _Float16* a22;
    float ir, jr;
};

__device__ __forceinline__ BLH mkh(const _Float16* __restrict__ base, int mm,
                                   float fi, float fj, int I, int J, int chan) {
    BLH b;
    int i1 = (int)floorf(fi);
    int j1 = (int)floorf(fj);
    b.ir = fi - (float)i1;
    b.jr = fj - (float)j1;
    int i2 = (i1 + 1 == I) ? 0 : (i1 + 1);
    int j2 = (j1 + 1 == J) ? 0 : (j1 + 1);
    const _Float16* p = base + ((size_t)mm * I * J) * Lc + chan;
    b.a11 = p + (size_t)(i1 * J + j1) * Lc;
    b.a21 = p + (size_t)(i2 * J + j1) * Lc;
    b.a12 = p + (size_t)(i1 * J + j2) * Lc;
    b.a22 = p + (size_t)(i2 * J + j2) * Lc;
    return b;
}

__device__ __forceinline__ h8 ldh(const _Float16* p) {
    return *reinterpret_cast<const h8*>(p);
}

__device__ __forceinline__ F8 blend8(h8 h11, h8 h21, h8 h12, h8 h22, float ir, float jr) {
    F8 c11 = cvt8(h11), c21 = cvt8(h21), c12 = cvt8(h12), c22 = cvt8(h22);
    float oir = 1.0f - ir, ojr = 1.0f - jr;
    F8 r;
    r.lo = (c11.lo * oir + c21.lo * ir) * ojr + (c12.lo * oir + c22.lo * ir) * jr;
    r.hi = (c11.hi * oir + c21.hi * ir) * ojr + (c12.hi * oir + c22.hi * ir) * jr;
    return r;
}

__global__ __launch_bounds__(256) void main_f16_kernel(
    const v4f* __restrict__ inds4, const unsigned int* __restrict__ keys,
    const _Float16* __restrict__ Hxy, const _Float16* __restrict__ Hxu,
    const _Float16* __restrict__ Hxv, const _Float16* __restrict__ Hyu,
    const _Float16* __restrict__ Hyv, const _Float16* __restrict__ Huv,
    float* __restrict__ out, int N, int nwg)
{
    // bijective XCD-chunked swizzle (m204 variant)
    int bid = blockIdx.x;
    int q = nwg >> 3, r = nwg & 7;
    int xcd = bid & 7, idx = bid >> 3;
    int swz = (xcd < r) ? (xcd * (q + 1) + idx) : (r * (q + 1) + (xcd - r) * q + idx);

    int t   = swz * 256 + threadIdx.x;
    int k   = t >> 1;     // sorted-point index
    int sub = t & 1;      // which 8-channel half
    if (k >= N) return;

    v4f inds = inds4[k];
    unsigned int key = keys[k];
    int mm = (int)(key >> 24);
    int n  = (int)(key & 0xFFFFFFu);
    float ind_hx = inds.x, ind_hy = inds.y, ind_u = inds.z, ind_v = inds.w;

    int chan = sub * 8;

    BLH b0 = mkh(Hxy, mm, ind_hx, ind_hy, HXc, HYc, chan);
    BLH b1 = mkh(Hxu, mm, ind_hx, ind_u,  HXc, Uc,  chan);
    BLH b2 = mkh(Hxv, mm, ind_hx, ind_v,  HXc, Vc,  chan);
    BLH b3 = mkh(Hyu, mm, ind_hy, ind_u,  HYc, Uc,  chan);
    BLH b4 = mkh(Hyv, mm, ind_hy, ind_v,  HYc, Vc,  chan);
    BLH b5 = mkh(Huv, mm, ind_u,  ind_v,  Uc,  Vc,  chan);

    // issue all 24 gathers before any consumption
    h8 c0a = ldh(b0.a11); h8 c0b = ldh(b0.a21); h8 c0c = ldh(b0.a12); h8 c0d = ldh(b0.a22);
    h8 c1a = ldh(b1.a11); h8 c1b = ldh(b1.a21); h8 c1c = ldh(b1.a12); h8 c1d = ldh(b1.a22);
    h8 c2a = ldh(b2.a11); h8 c2b = ldh(b2.a21); h8 c2c = ldh(b2.a12); h8 c2d = ldh(b2.a22);
    h8 c3a = ldh(b3.a11); h8 c3b = ldh(b3.a21); h8 c3c = ldh(b3.a12); h8 c3d = ldh(b3.a22);
    h8 c4a = ldh(b4.a11); h8 c4b = ldh(b4.a21); h8 c4c = ldh(b4.a12); h8 c4d = ldh(b4.a22);
    h8 c5a = ldh(b5.a11); h8 c5b = ldh(b5.a21); h8 c5c = ldh(b5.a12); h8 c5d = ldh(b5.a22);

    __builtin_amdgcn_sched_barrier(0);

    float* o = out + (size_t)n * 96 + chan;

    F8 r0 = blend8(c0a, c0b, c0c, c0d, b0.ir, b0.jr);
    *reinterpret_cast<v4f*>(o + 0 * Lc)     = r0.lo;
    *reinterpret_cast<v4f*>(o + 0 * Lc + 4) = r0.hi;
    F8 r1 = blend8(c1a, c1b, c1c, c1d, b1.ir, b1.jr);
    *reinterpret_cast<v4f*>(o + 1 * Lc)     = r1.lo;
    *reinterpret_cast<v4f*>(o + 1 * Lc + 4) = r1.hi;
    F8 r2 = blend8(c2a, c2b, c2c, c2d, b2.ir, b2.jr);
    *reinterpret_cast<v4f*>(o + 2 * Lc)     = r2.lo;
    *reinterpret_cast<v4f*>(o + 2 * Lc + 4) = r2.hi;
    F8 r3 = blend8(c3a, c3b, c3c, c3d, b3.ir, b3.jr);
    *reinterpret_cast<v4f*>(o + 3 * Lc)     = r3.lo;
    *reinterpret_cast<v4f*>(o + 3 * Lc + 4) = r3.hi;
    F8 r4 = blend8(c4a, c4b, c4c, c4d, b4.ir, b4.jr);
    *reinterpret_cast<v4f*>(o + 4 * Lc)     = r4.lo;
    *reinterpret_cast<v4f*>(o + 4 * Lc + 4) = r4.hi;
    F8 r5 = blend8(c5a, c5b, c5c, c5d, b5.ir, b5.jr);
    *reinterpret_cast<v4f*>(o + 5 * Lc)     = r5.lo;
    *reinterpret_cast<v4f*>(o + 5 * Lc + 4) = r5.hi;
}

// ---------------- pass 4 (f32 fallback): main gather, 4 threads/pt ----------------

struct BL {
    const float* a11; const float* a21; const float* a12; const float* a22;
    float ir, jr;
};

__device__ __forceinline__ v4f ld4(const float* p) {
    return *reinterpret_cast<const v4f*>(p);
}

__device__ __forceinline__ BL mk(const float* __restrict__ base, int mm,
                                 float fi, float fj, int I, int J, int chan) {
    BL b;
    int i1 = (int)floorf(fi);
    int j1 = (int)floorf(fj);
    b.ir = fi - (float)i1;
    b.jr = fj - (float)j1;
    int i2 = (i1 + 1 == I) ? 0 : (i1 + 1);
    int j2 = (j1 + 1 == J) ? 0 : (j1 + 1);
    const float* p = base + ((size_t)mm * I * J) * Lc + chan;
    b.a11 = p + (size_t)(i1 * J + j1) * Lc;
    b.a21 = p + (size_t)(i2 * J + j1) * Lc;
    b.a12 = p + (size_t)(i1 * J + j2) * Lc;
    b.a22 = p + (size_t)(i2 * J + j2) * Lc;
    return b;
}

__device__ __forceinline__ v4f blend(v4f c11, v4f c21, v4f c12, v4f c22,
                                     float ir, float jr) {
    float oir = 1.0f - ir;
    float ojr = 1.0f - jr;
    v4f top = c11 * oir + c21 * ir;
    v4f bot = c12 * oir + c22 * ir;
    return top * ojr + bot * jr;
}

__global__ __launch_bounds__(256) void main_f32_kernel(
    const v4f* __restrict__ inds4, const unsigned int* __restrict__ keys,
    const float* __restrict__ Fxy, const float* __restrict__ Fxu,
    const float* __restrict__ Fxv, const float* __restrict__ Fyu,
    const float* __restrict__ Fyv, const float* __restrict__ Fuv,
    float* __restrict__ out, int N, int nwg)
{
    int bid = blockIdx.x;
    int q = nwg >> 3, r = nwg & 7;
    int xcd = bid & 7, idx = bid >> 3;
    int swz = (xcd < r) ? (xcd * (q + 1) + idx) : (r * (q + 1) + (xcd - r) * q + idx);

    int t   = swz * 256 + threadIdx.x;
    int k   = t >> 2;
    int sub = t & 3;
    if (k >= N) return;

    v4f inds = inds4[k];
    unsigned int key = keys[k];
    int mm = (int)(key >> 24);
    int n  = (int)(key & 0xFFFFFFu);
    float ind_hx = inds.x, ind_hy = inds.y, ind_u = inds.z, ind_v = inds.w;

    int chan = sub * 4;

    BL b0 = mk(Fxy, mm, ind_hx, ind_hy, HXc, HYc, chan);
    BL b1 = mk(Fxu, mm, ind_hx, ind_u,  HXc, Uc,  chan);
    BL b2 = mk(Fxv, mm, ind_hx, ind_v,  HXc, Vc,  chan);
    BL b3 = mk(Fyu, mm, ind_hy, ind_u,  HYc, Uc,  chan);
    BL b4 = mk(Fyv, mm, ind_hy, ind_v,  HYc, Vc,  chan);
    BL b5 = mk(Fuv, mm, ind_u,  ind_v,  Uc,  Vc,  chan);

    v4f c0a = ld4(b0.a11); v4f c0b = ld4(b0.a21); v4f c0c = ld4(b0.a12); v4f c0d = ld4(b0.a22);
    v4f c1a = ld4(b1.a11); v4f c1b = ld4(b1.a21); v4f c1c = ld4(b1.a12); v4f c1d = ld4(b1.a22);
    v4f c2a = ld4(b2.a11); v4f c2b = ld4(b2.a21); v4f c2c = ld4(b2.a12); v4f c2d = ld4(b2.a22);
    v4f c3a = ld4(b3.a11); v4f c3b = ld4(b3.a21); v4f c3c = ld4(b3.a12); v4f c3d = ld4(b3.a22);
    v4f c4a = ld4(b4.a11); v4f c4b = ld4(b4.a21); v4f c4c = ld4(b4.a12); v4f c4d = ld4(b4.a22);
    v4f c5a = ld4(b5.a11); v4f c5b = ld4(b5.a21); v4f c5c = ld4(b5.a12); v4f c5d = ld4(b5.a22);

    __builtin_amdgcn_sched_barrier(0);

    float* o = out + (size_t)n * 96 + chan;
    *reinterpret_cast<v4f*>(o + 0 * Lc) = blend(c0a, c0b, c0c, c0d, b0.ir, b0.jr);
    *reinterpret_cast<v4f*>(o + 1 * Lc) = blend(c1a, c1b, c1c, c1d, b1.ir, b1.jr);
    *reinterpret_cast<v4f*>(o + 2 * Lc) = blend(c2a, c2b, c2c, c2d, b2.ir, b2.jr);
    *reinterpret_cast<v4f*>(o + 3 * Lc) = blend(c3a, c3b, c3c, c3d, b3.ir, b3.jr);
    *reinterpret_cast<v4f*>(o + 4 * Lc) = blend(c4a, c4b, c4c, c4d, b4.ir, b4.jr);
    *reinterpret_cast<v4f*>(o + 5 * Lc) = blend(c5a, c5b, c5c, c5d, b5.ir, b5.jr);
}

// ---------------- flat fallback (no workspace) ----------------

__global__ __launch_bounds__(256) void flat_kernel(
    const int*   __restrict__ m_arr,
    const float* __restrict__ h,
    const float* __restrict__ u_arr,
    const float* __restrict__ v_arr,
    const float* __restrict__ Fxy, const float* __restrict__ Fxu,
    const float* __restrict__ Fxv, const float* __restrict__ Fyu,
    const float* __restrict__ Fyv, const float* __restrict__ Fuv,
    float* __restrict__ out, int N)
{
    int tid = blockIdx.x * blockDim.x + threadIdx.x;
    int n   = tid >> 2;
    int sub = tid & 3;
    if (n >= N) return;

    float h0 = h[2 * n], h1 = h[2 * n + 1];
    float ind_hx, ind_hy, ind_u, ind_v;
    compute_inds(h0, h1, u_arr[n], v_arr[n], ind_hx, ind_hy, ind_u, ind_v);
    int mm = m_arr[n];
    int chan = sub * 4;

    BL b0 = mk(Fxy, mm, ind_hx, ind_hy, HXc, HYc, chan);
    BL b1 = mk(Fxu, mm, ind_hx, ind_u,  HXc, Uc,  chan);
    BL b2 = mk(Fxv, mm, ind_hx, ind_v,  HXc, Vc,  chan);
    BL b3 = mk(Fyu, mm, ind_hy, ind_u,  HYc, Uc,  chan);
    BL b4 = mk(Fyv, mm, ind_hy, ind_v,  HYc, Vc,  chan);
    BL b5 = mk(Fuv, mm, ind_u,  ind_v,  Uc,  Vc,  chan);

    v4f c0a = ld4(b0.a11); v4f c0b = ld4(b0.a21); v4f c0c = ld4(b0.a12); v4f c0d = ld4(b0.a22);
    v4f c1a = ld4(b1.a11); v4f c1b = ld4(b1.a21); v4f c1c = ld4(b1.a12); v4f c1d = ld4(b1.a22);
    v4f c2a = ld4(b2.a11); v4f c2b = ld4(b2.a21); v4f c2c = ld4(b2.a12); v4f c2d = ld4(b2.a22);
    v4f c3a = ld4(b3.a11); v4f c3b = ld4(b3.a21); v4f c3c = ld4(b3.a12); v4f c3d = ld4(b3.a22);
    v4f c4a = ld4(b4.a11); v4f c4b = ld4(b4.a21); v4f c4c = ld4(b4.a12); v4f c4d = ld4(b4.a22);
    v4f c5a = ld4(b5.a11); v4f c5b = ld4(b5.a21); v4f c5c = ld4(b5.a12); v4f c5d = ld4(b5.a22);

    __builtin_amdgcn_sched_barrier(0);

    float* o = out + (size_t)n * 96 + chan;
    *reinterpret_cast<v4f*>(o + 0 * Lc) = blend(c0a, c0b, c0c, c0d, b0.ir, b0.jr);
    *reinterpret_cast<v4f*>(o + 1 * Lc) = blend(c1a, c1b, c1c, c1d, b1.ir, b1.jr);
    *reinterpret_cast<v4f*>(o + 2 * Lc) = blend(c2a, c2b, c2c, c2d, b2.ir, b2.jr);
    *reinterpret_cast<v4f*>(o + 3 * Lc) = blend(c3a, c3b, c3c, c3d, b3.ir, b3.jr);
    *reinterpret_cast<v4f*>(o + 4 * Lc) = blend(c4a, c4b, c4c, c4d, b4.ir, b4.jr);
    *reinterpret_cast<v4f*>(o + 5 * Lc) = blend(c5a, c5b, c5c, c5d, b5.ir, b5.jr);
}

// ---------------- host launch ----------------

extern "C" void kernel_launch(void* const* d_in, const int* in_sizes, int n_in,
                              void* d_out, int out_size, void* d_ws, size_t ws_size,
                              hipStream_t stream) {
    // setup_inputs order: r(unused), m, h, u, v, Fxy, Fxu, Fxv, Fyu, Fyv, Fuv
    const int*   m_arr = (const int*)  d_in[1];
    const float* h     = (const float*)d_in[2];
    const float* u_arr = (const float*)d_in[3];
    const float* v_arr = (const float*)d_in[4];
    const float* Fxy   = (const float*)d_in[5];
    const float* Fxu   = (const float*)d_in[6];
    const float* Fxv   = (const float*)d_in[7];
    const float* Fyu   = (const float*)d_in[8];
    const float* Fyv   = (const float*)d_in[9];
    const float* Fuv   = (const float*)d_in[10];
    float* out = (float*)d_out;

    int N = in_sizes[0];

    // table element counts
    const size_t SZ_xy = (size_t)8 * 64 * 64 * 16;     //   524,288
    const size_t SZ_mid = (size_t)8 * 64 * 512 * 16;   // 4,194,304 (xu, xv, yu, yv)
    const size_t SZ_uv = (size_t)8 * 512 * 512 * 16;   // 33,554,432
    const size_t SZ_half_total = SZ_xy + 4 * SZ_mid + SZ_uv;  // 50,855,936

    // fp16-path workspace layout (all offsets 16-B aligned)
    size_t off_hxy   = 0;
    size_t off_hxu   = off_hxy + SZ_xy * 2;
    size_t off_hxv   = off_hxu + SZ_mid * 2;
    size_t off_hyu   = off_hxv + SZ_mid * 2;
    size_t off_hyv   = off_hyu + SZ_mid * 2;
    size_t off_huv   = off_hyv + SZ_mid * 2;
    size_t off_counts  = off_huv + SZ_uv * 2;
    size_t off_cursors = off_counts  + (size_t)NBUCK * 4;
    size_t off_inds4   = off_cursors + (size_t)NBUCK * 4;
    size_t off_keys    = off_inds4   + (size_t)N * 16;
    size_t need_f16    = off_keys    + (size_t)N * 4;

    // f32-sorted fallback layout
    size_t f32_counts  = 0;
    size_t f32_cursors = f32_counts  + (size_t)NBUCK * 4;
    size_t f32_inds4   = f32_cursors + (size_t)NBUCK * 4;
    size_t f32_keys    = f32_inds4   + (size_t)N * 16;
    size_t need_f32    = f32_keys    + (size_t)N * 4;

    dim3 blk(256);
    dim3 grdN((N + 255) / 256);
    char* ws = (char*)d_ws;

    if (ws != nullptr && ws_size >= need_f16) {
        _Float16* Hxy = (_Float16*)(ws + off_hxy);
        _Float16* Hxu = (_Float16*)(ws + off_hxu);
        _Float16* Hxv = (_Float16*)(ws + off_hxv);
        _Float16* Hyu = (_Float16*)(ws + off_hyu);
        _Float16* Hyv = (_Float16*)(ws + off_hyv);
        _Float16* Huv = (_Float16*)(ws + off_huv);
        int* counts  = (int*)(ws + off_counts);
        int* cursors = (int*)(ws + off_cursors);
        v4f* inds4   = (v4f*)(ws + off_inds4);
        unsigned int* keys = (unsigned int*)(ws + off_keys);

        // convert tables to fp16
        int n8_xy  = (int)(SZ_xy  / 8);
        int n8_mid = (int)(SZ_mid / 8);
        int n8_uv  = (int)(SZ_uv  / 8);
        convert_kernel<<<dim3((n8_xy  + 255) / 256), blk, 0, stream>>>(Fxy, Hxy, n8_xy);
        convert_kernel<<<dim3((n8_mid + 255) / 256), blk, 0, stream>>>(Fxu, Hxu, n8_mid);
        convert_kernel<<<dim3((n8_mid + 255) / 256), blk, 0, stream>>>(Fxv, Hxv, n8_mid);
        convert_kernel<<<dim3((n8_mid + 255) / 256), blk, 0, stream>>>(Fyu, Hyu, n8_mid);
        convert_kernel<<<dim3((n8_mid + 255) / 256), blk, 0, stream>>>(Fyv, Hyv, n8_mid);
        convert_kernel<<<dim3((n8_uv  + 255) / 256), blk, 0, stream>>>(Fuv, Huv, n8_uv);

        zero_kernel<<<dim3((NBUCK + 255) / 256), blk, 0, stream>>>(counts);
        hist_kernel<<<dim3((N / 4 + 255) / 256), blk, 0, stream>>>(m_arr, u_arr, v_arr, counts, N);
        scan_kernel<<<dim3(1), dim3(1024), 0, stream>>>(counts, cursors);
        scatter_kernel<<<grdN, blk, 0, stream>>>(m_arr, h, u_arr, v_arr, cursors,
                                                 inds4, keys, N);

        int total_threads = 2 * N;
        int nwg = (total_threads + 255) / 256;
        main_f16_kernel<<<dim3(nwg), blk, 0, stream>>>(inds4, keys,
                                                       Hxy, Hxu, Hxv, Hyu, Hyv, Huv,
                                                       out, N, nwg);
    } else if (ws != nullptr && ws_size >= need_f32) {
        int* counts  = (int*)(ws + f32_counts);
        int* cursors = (int*)(ws + f32_cursors);
        v4f* inds4   = (v4f*)(ws + f32_inds4);
        unsigned int* keys = (unsigned int*)(ws + f32_keys);

        zero_kernel<<<dim3((NBUCK + 255) / 256), blk, 0, stream>>>(counts);
        hist_kernel<<<dim3((N / 4 + 255) / 256), blk, 0, stream>>>(m_arr, u_arr, v_arr, counts, N);
        scan_kernel<<<dim3(1), dim3(1024), 0, stream>>>(counts, cursors);
        scatter_kernel<<<grdN, blk, 0, stream>>>(m_arr, h, u_arr, v_arr, cursors,
                                                 inds4, keys, N);

        int total_threads = 4 * N;
        int nwg = (total_threads + 255) / 256;
        main_f32_kernel<<<dim3(nwg), blk, 0, stream>>>(inds4, keys,
                                                       Fxy, Fxu, Fxv, Fyu, Fyv, Fuv,
                                                       out, N, nwg);
    } else {
        int total_threads = 4 * N;
        dim3 grid((total_threads + 255) / 256);
        flat_kernel<<<grid, blk, 0, stream>>>(m_arr, h, u_arr, v_arr,
                                              Fxy, Fxu, Fxv, Fyu, Fyv, Fuv, out, N);
    }
}